// Round 1
// baseline (816.966 us; speedup 1.0000x reference)
//
#include <hip/hip_runtime.h>
#include <hip/hip_bf16.h>
#include <cmath>

// Problem constants
#define B_   8
#define N_   4096
#define DIN1 64
#define DHID 128
#define DOUT2 64
#define MAXDEG 256

// ---------------------------------------------------------------------------
// Wave reduction helpers (wave = 64 lanes on CDNA)
// ---------------------------------------------------------------------------
__device__ __forceinline__ float wave_reduce_sum(float v) {
#pragma unroll
    for (int off = 32; off > 0; off >>= 1) v += __shfl_down(v, off, 64);
    return v;  // lane 0 holds the total
}
__device__ __forceinline__ float wave_reduce_max(float v) {
#pragma unroll
    for (int off = 32; off > 0; off >>= 1) v = fmaxf(v, __shfl_down(v, off, 64));
    return v;  // lane 0 holds the max
}

// ---------------------------------------------------------------------------
// Kernel 1: build fixed-stride neighbor lists from the dense adjacency.
// One block per row n; coalesced scan of graph[n, :].
// ---------------------------------------------------------------------------
__global__ __launch_bounds__(256) void k_build_csr(
    const float* __restrict__ graph, int* __restrict__ cnt, int* __restrict__ idx)
{
    const int n = blockIdx.x;
    __shared__ int lcnt;
    if (threadIdx.x == 0) lcnt = 0;
    __syncthreads();
    const float* row = graph + (size_t)n * N_;
    for (int m = threadIdx.x; m < N_; m += 256) {
        if (row[m] != 0.0f) {
            int p = atomicAdd(&lcnt, 1);
            if (p < MAXDEG) idx[(size_t)n * MAXDEG + p] = m;
        }
    }
    __syncthreads();
    if (threadIdx.x == 0) cnt[n] = (lcnt < MAXDEG) ? lcnt : MAXDEG;
}

// ---------------------------------------------------------------------------
// Kernel 2: h[r, k] = sum_d x[r, d] * W[k, d]   (r = b*N + n, W is [DOUT,DIN])
// W staged in LDS with +1 padding (stride DIN+1 -> bank (k+d)%32, conflict-free).
// ---------------------------------------------------------------------------
template <int DIN, int DOUT>
__global__ __launch_bounds__(256) void k_linear(
    const float* __restrict__ x, const float* __restrict__ W, float* __restrict__ out)
{
    constexpr int RPI  = 256 / DOUT;  // rows computed per iteration
    constexpr int ROWS = 32;          // rows per block
    __shared__ float sW[DOUT][DIN + 1];
    __shared__ float sx[RPI][DIN];

    const int t = threadIdx.x;
    for (int i = t; i < DOUT * DIN; i += 256) sW[i / DIN][i % DIN] = W[i];

    const int base = blockIdx.x * ROWS;
    const int rr = t / DOUT;
    const int kk = t % DOUT;

    for (int r0 = 0; r0 < ROWS; r0 += RPI) {
        __syncthreads();  // protect sx reuse (also covers first sW use)
        for (int i = t; i < RPI * DIN; i += 256) {
            int r = i / DIN, d = i % DIN;
            sx[r][d] = x[(size_t)(base + r0 + r) * DIN + d];
        }
        __syncthreads();
        float acc = 0.0f;
#pragma unroll
        for (int d = 0; d < DIN; ++d) acc += sx[rr][d] * sW[kk][d];
        out[(size_t)(base + r0 + rr) * DOUT + kk] = acc;
    }
}

// ---------------------------------------------------------------------------
// Kernel 3: column sums of h per batch (for the all-masked-row uniform
// softmax fallback: out = mean_m h[b,m,:]). cm must be pre-zeroed.
// ---------------------------------------------------------------------------
__global__ __launch_bounds__(256) void k_colsum(
    const float* __restrict__ h, float* __restrict__ cm, int D)
{
    const int b = blockIdx.x;
    const int chunk = blockIdx.y;           // 16 chunks of 256 rows
    const int t = threadIdx.x;
    const int G = 256 / D;
    const int d = t % D;
    const int g = t / D;
    const int n0 = chunk * 256;
    float acc = 0.0f;
    for (int n = n0 + g; n < n0 + 256; n += G)
        acc += h[((size_t)b * N_ + n) * D + d];
    atomicAdd(&cm[b * D + d], acc);
}

// ---------------------------------------------------------------------------
// Kernel 4: sparse masked attention for one (n, b) per block.
//   scores: wave-per-neighbor, coalesced 256B row loads, shuffle-reduce dot
//   softmax: LDS, exact reference semantics (dot==0 => masked; all-masked =>
//            uniform over all 4096 rows via precomputed column sums)
//   aggregate: dim-per-thread, 256/D neighbor groups, LDS cross-group reduce
// ---------------------------------------------------------------------------
template <int D, bool RELU>
__global__ __launch_bounds__(256) void k_attn(
    const float* __restrict__ h, const int* __restrict__ cnt,
    const int* __restrict__ idx, const float* __restrict__ bias,
    const float* __restrict__ colsum, float* __restrict__ out)
{
    const int n = blockIdx.x;
    const int b = blockIdx.y;
    const int t = threadIdx.x;
    const int lane = t & 63;
    const int wave = t >> 6;

    __shared__ int   s_nbr[MAXDEG];
    __shared__ float s_sc[MAXDEG];
    __shared__ float s_q[D];
    __shared__ float s_red[4];
    __shared__ float s_acc[256];

    const int k = cnt[n];
    for (int j = t; j < k; j += 256) s_nbr[j] = idx[(size_t)n * MAXDEG + j];
    const float* __restrict__ hb = h + (size_t)b * N_ * D;
    for (int d = t; d < D; d += 256) s_q[d] = hb[(size_t)n * D + d];
    __syncthreads();

    float q0 = s_q[lane];
    float q1 = 0.0f;
    if constexpr (D == 128) q1 = s_q[lane + 64];

    // --- scores ---
    for (int j = wave; j < k; j += 4) {
        const float* hm = hb + (size_t)s_nbr[j] * D;
        float p = q0 * hm[lane];
        if constexpr (D == 128) p += q1 * hm[lane + 64];
        p = wave_reduce_sum(p);
        if (lane == 0) s_sc[j] = p;
    }
    __syncthreads();

    // --- masked max ---
    float lm = -INFINITY;
    for (int j = t; j < k; j += 256) {
        float v = s_sc[j];
        if (v != 0.0f) lm = fmaxf(lm, v);  // dot==0 (incl -0) => masked_fill(NEG)
    }
    lm = wave_reduce_max(lm);
    if (lane == 0) s_red[wave] = lm;
    __syncthreads();
    const float mx = fmaxf(fmaxf(s_red[0], s_red[1]), fmaxf(s_red[2], s_red[3]));
    __syncthreads();

    // --- exp + sum ---
    float ls = 0.0f;
    for (int j = t; j < k; j += 256) {
        float v = s_sc[j];
        float w = (v != 0.0f) ? __expf(v - mx) : 0.0f;
        s_sc[j] = w;
        ls += w;
    }
    ls = wave_reduce_sum(ls);
    if (lane == 0) s_red[wave] = ls;
    __syncthreads();
    const float sum = s_red[0] + s_red[1] + s_red[2] + s_red[3];

    // --- aggregate ---
    constexpr int G = 256 / D;
    const int d = t % D;
    const int g = t / D;
    float acc = 0.0f;
    if (sum > 0.0f) {
        for (int j = g; j < k; j += G)
            acc += s_sc[j] * hb[(size_t)s_nbr[j] * D + d];
    }
    s_acc[t] = acc;
    __syncthreads();
    if (g == 0) {
#pragma unroll
        for (int gg = 1; gg < G; ++gg) acc += s_acc[gg * D + d];
        float o;
        if (sum > 0.0f) o = acc / sum + bias[d];
        else            o = colsum[b * D + d] * (1.0f / (float)N_) + bias[d];
        if (RELU) o = fmaxf(o, 0.0f);
        out[((size_t)b * N_ + n) * D + d] = o;
    }
}

// ---------------------------------------------------------------------------
// Launch
// ---------------------------------------------------------------------------
extern "C" void kernel_launch(void* const* d_in, const int* in_sizes, int n_in,
                              void* d_out, int out_size, void* d_ws, size_t ws_size,
                              hipStream_t stream) {
    (void)in_sizes; (void)n_in; (void)out_size; (void)ws_size;

    const float* flow_x = (const float*)d_in[0];
    const float* graph  = (const float*)d_in[1];
    const float* W1     = (const float*)d_in[2];
    const float* b1     = (const float*)d_in[3];
    const float* W2     = (const float*)d_in[4];
    const float* b2     = (const float*)d_in[5];
    float* out = (float*)d_out;

    char* p = (char*)d_ws;
    auto carve = [&](size_t bytes) -> void* {
        void* r = (void*)p;
        p += (bytes + 255) & ~(size_t)255;
        return r;
    };
    int*   nbr_cnt = (int*)carve((size_t)N_ * sizeof(int));
    int*   nbr_idx = (int*)carve((size_t)N_ * MAXDEG * sizeof(int));
    float* h1      = (float*)carve((size_t)B_ * N_ * DHID * sizeof(float));
    float* x2      = (float*)carve((size_t)B_ * N_ * DHID * sizeof(float));
    float* h2      = (float*)carve((size_t)B_ * N_ * DOUT2 * sizeof(float));
    float* cm1     = (float*)carve((size_t)B_ * DHID * sizeof(float));
    float* cm2     = (float*)carve((size_t)B_ * DOUT2 * sizeof(float));

    // 1. adjacency -> neighbor lists (shared by both layers, all batches)
    k_build_csr<<<N_, 256, 0, stream>>>(graph, nbr_cnt, nbr_idx);

    // 2. layer 1: h1 = flow_x . W1^T
    k_linear<DIN1, DHID><<<(B_ * N_) / 32, 256, 0, stream>>>(flow_x, W1, h1);

    // 3. column sums for uniform-softmax fallback
    hipMemsetAsync(cm1, 0, (size_t)B_ * DHID * sizeof(float), stream);
    k_colsum<<<dim3(B_, 16), 256, 0, stream>>>(h1, cm1, DHID);

    // 4. layer 1 attention + bias + relu -> x2
    k_attn<DHID, true><<<dim3(N_, B_), 256, 0, stream>>>(h1, nbr_cnt, nbr_idx, b1, cm1, x2);

    // 5. layer 2: h2 = x2 . W2^T
    k_linear<DHID, DOUT2><<<(B_ * N_) / 32, 256, 0, stream>>>(x2, W2, h2);

    // 6. column sums for fallback
    hipMemsetAsync(cm2, 0, (size_t)B_ * DOUT2 * sizeof(float), stream);
    k_colsum<<<dim3(B_, 16), 256, 0, stream>>>(h2, cm2, DOUT2);

    // 7. layer 2 attention + bias -> d_out  ([B,N,1,64] is flat-identical)
    k_attn<DOUT2, false><<<dim3(N_, B_), 256, 0, stream>>>(h2, nbr_cnt, nbr_idx, b2, cm2, out);
}

// Round 2
// 431.929 us; speedup vs baseline: 1.8914x; 1.8914x over previous
//
#include <hip/hip_runtime.h>
#include <hip/hip_bf16.h>
#include <cmath>

// Problem constants
#define B_   8
#define N_   4096
#define DIN1 64
#define DHID 128
#define DOUT2 64
#define MAXDEG 256

// ---------------------------------------------------------------------------
// Wave reduction helpers (wave = 64 lanes on CDNA)
// ---------------------------------------------------------------------------
__device__ __forceinline__ float wave_reduce_sum(float v) {
#pragma unroll
    for (int off = 32; off > 0; off >>= 1) v += __shfl_down(v, off, 64);
    return v;  // lane 0 holds the total
}
__device__ __forceinline__ float wave_reduce_max(float v) {
#pragma unroll
    for (int off = 32; off > 0; off >>= 1) v = fmaxf(v, __shfl_down(v, off, 64));
    return v;  // lane 0 holds the max
}

// ---------------------------------------------------------------------------
// Kernel 1: build fixed-stride neighbor lists from the dense adjacency.
// ---------------------------------------------------------------------------
__global__ __launch_bounds__(256) void k_build_csr(
    const float* __restrict__ graph, int* __restrict__ cnt, int* __restrict__ idx)
{
    const int n = blockIdx.x;
    __shared__ int lcnt;
    if (threadIdx.x == 0) lcnt = 0;
    __syncthreads();
    const float* row = graph + (size_t)n * N_;
    for (int m = threadIdx.x; m < N_; m += 256) {
        if (row[m] != 0.0f) {
            int p = atomicAdd(&lcnt, 1);
            if (p < MAXDEG) idx[(size_t)n * MAXDEG + p] = m;
        }
    }
    __syncthreads();
    if (threadIdx.x == 0) cnt[n] = (lcnt < MAXDEG) ? lcnt : MAXDEG;
}

// ---------------------------------------------------------------------------
// Kernel 2: h[r, k] = sum_d x[r, d] * W[k, d]
// ---------------------------------------------------------------------------
template <int DIN, int DOUT>
__global__ __launch_bounds__(256) void k_linear(
    const float* __restrict__ x, const float* __restrict__ W, float* __restrict__ out)
{
    constexpr int RPI  = 256 / DOUT;
    constexpr int ROWS = 32;
    __shared__ float sW[DOUT][DIN + 1];
    __shared__ float sx[RPI][DIN];

    const int t = threadIdx.x;
    for (int i = t; i < DOUT * DIN; i += 256) sW[i / DIN][i % DIN] = W[i];

    const int base = blockIdx.x * ROWS;
    const int rr = t / DOUT;
    const int kk = t % DOUT;

    for (int r0 = 0; r0 < ROWS; r0 += RPI) {
        __syncthreads();
        for (int i = t; i < RPI * DIN; i += 256) {
            int r = i / DIN, d = i % DIN;
            sx[r][d] = x[(size_t)(base + r0 + r) * DIN + d];
        }
        __syncthreads();
        float acc = 0.0f;
#pragma unroll
        for (int d = 0; d < DIN; ++d) acc += sx[rr][d] * sW[kk][d];
        out[(size_t)(base + r0 + rr) * DOUT + kk] = acc;
    }
}

// ---------------------------------------------------------------------------
// Kernel 3: column sums of h per batch (all-masked-row fallback). Pre-zeroed.
// ---------------------------------------------------------------------------
__global__ __launch_bounds__(256) void k_colsum(
    const float* __restrict__ h, float* __restrict__ cm, int D)
{
    const int b = blockIdx.x;
    const int chunk = blockIdx.y;
    const int t = threadIdx.x;
    const int G = 256 / D;
    const int d = t % D;
    const int g = t / D;
    const int n0 = chunk * 256;
    float acc = 0.0f;
    for (int n = n0 + g; n < n0 + 256; n += G)
        acc += h[((size_t)b * N_ + n) * D + d];
    atomicAdd(&cm[b * D + d], acc);
}

// ---------------------------------------------------------------------------
// Kernel 4: sparse masked attention. 1-D grid of N*B blocks; b = id & 7 so
// each batch pins to one XCD (round-robin dispatch heuristic; h[b]=2MB fits
// the 4MB per-XCD L2). Scores: 16 lanes/neighbor, float4 loads, 4-deep shfl
// reduce. Aggregate: float4 per thread. Exact reference mask semantics.
// ---------------------------------------------------------------------------
template <int D, bool RELU>
__global__ __launch_bounds__(256) void k_attn(
    const float* __restrict__ h, const int* __restrict__ cnt,
    const int* __restrict__ idx, const float* __restrict__ bias,
    const float* __restrict__ colsum, float* __restrict__ out)
{
    constexpr int V = D / 4;        // float4s per row (32 or 16)
    const int bid = blockIdx.x;
    const int b = bid & 7;
    const int n = bid >> 3;
    const int t = threadIdx.x;
    const int lane = t & 63;
    const int wave = t >> 6;
    const int grp = t >> 4;         // 16 groups of 16 lanes
    const int gl  = t & 15;

    __shared__ int    s_nbr[MAXDEG];
    __shared__ float  s_sc[MAXDEG];
    __shared__ float4 s_q[V];
    __shared__ float  s_red[4];
    __shared__ float4 s_acc[256];

    const int k = cnt[n];
    for (int j = t; j < k; j += 256) s_nbr[j] = idx[(size_t)n * MAXDEG + j];
    const float4* __restrict__ hb4 = (const float4*)(h + (size_t)b * N_ * D);
    if (t < V) s_q[t] = hb4[(size_t)n * V + t];
    __syncthreads();

    // q fragment: lane gl owns elements [8*gl, 8*gl+8) for D=128, [4*gl,..) for 64
    float4 q0 = s_q[gl];
    float4 q1;
    if constexpr (D == 128) q1 = s_q[gl + 16];

    // --- scores: 16 lanes per neighbor, 16 neighbors in flight per block ---
    for (int j = grp; j < k; j += 16) {
        const float4* hm = hb4 + (size_t)s_nbr[j] * V;
        float p;
        if constexpr (D == 128) {
            float4 a = hm[gl];
            float4 c = hm[gl + 16];
            p = q0.x * a.x + q0.y * a.y + q0.z * a.z + q0.w * a.w
              + q1.x * c.x + q1.y * c.y + q1.z * c.z + q1.w * c.w;
        } else {
            float4 a = hm[gl];
            p = q0.x * a.x + q0.y * a.y + q0.z * a.z + q0.w * a.w;
        }
        p += __shfl_down(p, 8, 64);
        p += __shfl_down(p, 4, 64);
        p += __shfl_down(p, 2, 64);
        p += __shfl_down(p, 1, 64);
        if (gl == 0) s_sc[j] = p;
    }
    __syncthreads();

    // --- masked max (dot==0 => masked_fill(NEG), torch semantics) ---
    float lm = -INFINITY;
    for (int j = t; j < k; j += 256) {
        float v = s_sc[j];
        if (v != 0.0f) lm = fmaxf(lm, v);
    }
    lm = wave_reduce_max(lm);
    if (lane == 0) s_red[wave] = lm;
    __syncthreads();
    const float mx = fmaxf(fmaxf(s_red[0], s_red[1]), fmaxf(s_red[2], s_red[3]));
    __syncthreads();

    // --- exp + sum ---
    float ls = 0.0f;
    for (int j = t; j < k; j += 256) {
        float v = s_sc[j];
        float w = (v != 0.0f) ? __expf(v - mx) : 0.0f;
        s_sc[j] = w;
        ls += w;
    }
    ls = wave_reduce_sum(ls);
    if (lane == 0) s_red[wave] = ls;
    __syncthreads();
    const float sum = s_red[0] + s_red[1] + s_red[2] + s_red[3];

    // --- aggregate: thread owns float4 slice v, G neighbor-groups ---
    constexpr int G = 256 / V;      // 8 for D=128, 16 for D=64
    const int v = t % V;
    const int g = t / V;
    float4 acc = {0.0f, 0.0f, 0.0f, 0.0f};
    if (sum > 0.0f) {
        for (int j = g; j < k; j += G) {
            float w = s_sc[j];
            float4 hm = hb4[(size_t)s_nbr[j] * V + v];
            acc.x += w * hm.x;
            acc.y += w * hm.y;
            acc.z += w * hm.z;
            acc.w += w * hm.w;
        }
    }
    s_acc[t] = acc;
    __syncthreads();
    if (g == 0) {
#pragma unroll
        for (int gg = 1; gg < G; ++gg) {
            float4 o = s_acc[gg * V + v];
            acc.x += o.x; acc.y += o.y; acc.z += o.z; acc.w += o.w;
        }
        const float4 bi = ((const float4*)bias)[v];
        float4 o;
        if (sum > 0.0f) {
            const float inv = 1.0f / sum;
            o.x = acc.x * inv + bi.x;
            o.y = acc.y * inv + bi.y;
            o.z = acc.z * inv + bi.z;
            o.w = acc.w * inv + bi.w;
        } else {
            const float4 cs = ((const float4*)colsum)[b * V + v];
            constexpr float invN = 1.0f / (float)N_;
            o.x = cs.x * invN + bi.x;
            o.y = cs.y * invN + bi.y;
            o.z = cs.z * invN + bi.z;
            o.w = cs.w * invN + bi.w;
        }
        if (RELU) {
            o.x = fmaxf(o.x, 0.0f);
            o.y = fmaxf(o.y, 0.0f);
            o.z = fmaxf(o.z, 0.0f);
            o.w = fmaxf(o.w, 0.0f);
        }
        ((float4*)out)[((size_t)b * N_ + n) * V + v] = o;
    }
}

// ---------------------------------------------------------------------------
// Launch
// ---------------------------------------------------------------------------
extern "C" void kernel_launch(void* const* d_in, const int* in_sizes, int n_in,
                              void* d_out, int out_size, void* d_ws, size_t ws_size,
                              hipStream_t stream) {
    (void)in_sizes; (void)n_in; (void)out_size; (void)ws_size;

    const float* flow_x = (const float*)d_in[0];
    const float* graph  = (const float*)d_in[1];
    const float* W1     = (const float*)d_in[2];
    const float* b1     = (const float*)d_in[3];
    const float* W2     = (const float*)d_in[4];
    const float* b2     = (const float*)d_in[5];
    float* out = (float*)d_out;

    char* p = (char*)d_ws;
    auto carve = [&](size_t bytes) -> void* {
        void* r = (void*)p;
        p += (bytes + 255) & ~(size_t)255;
        return r;
    };
    int*   nbr_cnt = (int*)carve((size_t)N_ * sizeof(int));
    int*   nbr_idx = (int*)carve((size_t)N_ * MAXDEG * sizeof(int));
    float* h1      = (float*)carve((size_t)B_ * N_ * DHID * sizeof(float));
    float* x2      = (float*)carve((size_t)B_ * N_ * DHID * sizeof(float));
    float* h2      = (float*)carve((size_t)B_ * N_ * DOUT2 * sizeof(float));
    float* cm1     = (float*)carve((size_t)B_ * DHID * sizeof(float));
    float* cm2     = (float*)carve((size_t)B_ * DOUT2 * sizeof(float));

    // 1. adjacency -> neighbor lists
    k_build_csr<<<N_, 256, 0, stream>>>(graph, nbr_cnt, nbr_idx);

    // 2. layer 1 linear
    k_linear<DIN1, DHID><<<(B_ * N_) / 32, 256, 0, stream>>>(flow_x, W1, h1);

    // 3. column sums (fallback)
    hipMemsetAsync(cm1, 0, (size_t)B_ * DHID * sizeof(float), stream);
    k_colsum<<<dim3(B_, 16), 256, 0, stream>>>(h1, cm1, DHID);

    // 4. layer 1 attention + bias + relu
    k_attn<DHID, true><<<N_ * B_, 256, 0, stream>>>(h1, nbr_cnt, nbr_idx, b1, cm1, x2);

    // 5. layer 2 linear
    k_linear<DHID, DOUT2><<<(B_ * N_) / 32, 256, 0, stream>>>(x2, W2, h2);

    // 6. column sums (fallback)
    hipMemsetAsync(cm2, 0, (size_t)B_ * DOUT2 * sizeof(float), stream);
    k_colsum<<<dim3(B_, 16), 256, 0, stream>>>(h2, cm2, DOUT2);

    // 7. layer 2 attention + bias -> d_out
    k_attn<DOUT2, false><<<N_ * B_, 256, 0, stream>>>(h2, nbr_cnt, nbr_idx, b2, cm2, out);
}

// Round 3
// 362.286 us; speedup vs baseline: 2.2550x; 1.1922x over previous
//
#include <hip/hip_runtime.h>
#include <hip/hip_bf16.h>
#include <cmath>

// Problem constants
#define B_   8
#define N_   4096
#define DIN1 64
#define DHID 128
#define DOUT2 64
#define MAXDEG 256

// ---------------------------------------------------------------------------
// Wave reduction helpers (wave = 64 lanes on CDNA)
// ---------------------------------------------------------------------------
__device__ __forceinline__ float wave_reduce_sum(float v) {
#pragma unroll
    for (int off = 32; off > 0; off >>= 1) v += __shfl_down(v, off, 64);
    return v;
}
__device__ __forceinline__ float wave_reduce_max(float v) {
#pragma unroll
    for (int off = 32; off > 0; off >>= 1) v = fmaxf(v, __shfl_down(v, off, 64));
    return v;
}

// ---------------------------------------------------------------------------
// Kernel 1: adjacency -> fixed-stride neighbor lists. Blocks 0..7 also zero
// the column-sum fallback buffers (runs before the linears, stream-ordered).
// ---------------------------------------------------------------------------
__global__ __launch_bounds__(256) void k_build_csr(
    const float* __restrict__ graph, int* __restrict__ cnt, int* __restrict__ idx,
    float* __restrict__ cm1, float* __restrict__ cm2)
{
    const int n = blockIdx.x;
    if (n < B_) {
        for (int i = threadIdx.x; i < DHID; i += 256) cm1[n * DHID + i] = 0.0f;
        for (int i = threadIdx.x; i < DOUT2; i += 256) cm2[n * DOUT2 + i] = 0.0f;
    }
    __shared__ int lcnt;
    if (threadIdx.x == 0) lcnt = 0;
    __syncthreads();
    const float* row = graph + (size_t)n * N_;
    for (int m = threadIdx.x; m < N_; m += 256) {
        if (row[m] != 0.0f) {
            int p = atomicAdd(&lcnt, 1);
            if (p < MAXDEG) idx[(size_t)n * MAXDEG + p] = m;
        }
    }
    __syncthreads();
    if (threadIdx.x == 0) cnt[n] = (lcnt < MAXDEG) ? lcnt : MAXDEG;
}

// ---------------------------------------------------------------------------
// Kernel 2: h[r,k] = sum_d x[r,d]*W[k,d], fused per-batch column sums into cm
// (for the all-masked-row uniform-softmax fallback). One block = 32 rows, all
// in the same batch (4096 % 32 == 0).
// ---------------------------------------------------------------------------
template <int DIN, int DOUT>
__global__ __launch_bounds__(256) void k_linear(
    const float* __restrict__ x, const float* __restrict__ W,
    float* __restrict__ out, float* __restrict__ cm)
{
    constexpr int RPI  = 256 / DOUT;
    constexpr int ROWS = 32;
    __shared__ float sW[DOUT][DIN + 1];
    __shared__ float sx[RPI][DIN];
    __shared__ float scol[DOUT];

    const int t = threadIdx.x;
    for (int i = t; i < DOUT * DIN; i += 256) sW[i / DIN][i % DIN] = W[i];
    if (t < DOUT) scol[t] = 0.0f;

    const int base = blockIdx.x * ROWS;
    const int b = base / N_;
    const int rr = t / DOUT;
    const int kk = t % DOUT;
    float colacc = 0.0f;

    for (int r0 = 0; r0 < ROWS; r0 += RPI) {
        __syncthreads();
        for (int i = t; i < RPI * DIN; i += 256) {
            int r = i / DIN, d = i % DIN;
            sx[r][d] = x[(size_t)(base + r0 + r) * DIN + d];
        }
        __syncthreads();
        float acc = 0.0f;
#pragma unroll
        for (int d = 0; d < DIN; ++d) acc += sx[rr][d] * sW[kk][d];
        out[(size_t)(base + r0 + rr) * DOUT + kk] = acc;
        colacc += acc;
    }
    __syncthreads();
    atomicAdd(&scol[kk], colacc);     // RPI-way LDS contention, cheap
    __syncthreads();
    if (t < DOUT) atomicAdd(&cm[b * DOUT + t], scol[t]);
}

// ---------------------------------------------------------------------------
// Kernel 3: sparse masked attention. b = blockIdx & 7 pins batches to XCDs.
// Scores: 8 lanes/neighbor, 32 neighbors in flight, independent float4 loads,
// 3-deep shuffle reduce. Aggregate: 2-way unrolled float4 gathers. Exact
// torch masked_fill(s==0) semantics + uniform-softmax fallback via colsum.
// ---------------------------------------------------------------------------
template <int D, bool RELU>
__global__ __launch_bounds__(256) void k_attn(
    const float* __restrict__ h, const int* __restrict__ cnt,
    const int* __restrict__ idx, const float* __restrict__ bias,
    const float* __restrict__ colsum, float* __restrict__ out)
{
    constexpr int V  = D / 4;          // float4s per row (32 or 16)
    constexpr int NQ = V / 8;          // float4s per lane in score phase (4 or 2)
    const int bid = blockIdx.x;
    const int b = bid & 7;
    const int n = bid >> 3;
    const int t = threadIdx.x;
    const int lane = t & 63;
    const int wave = t >> 6;
    const int grp = t >> 3;            // 32 groups of 8 lanes
    const int gl  = t & 7;

    __shared__ int    s_nbr[MAXDEG];
    __shared__ float  s_sc[MAXDEG];
    __shared__ float  s_red[4];
    __shared__ float4 s_acc[256];

    const int k = cnt[n];
    for (int j = t; j < k; j += 256) s_nbr[j] = idx[(size_t)n * MAXDEG + j];
    const float4* __restrict__ hb4 = (const float4*)(h + (size_t)b * N_ * D);

    // q fragment straight from global (row n broadcast, L1-resident)
    float4 q[NQ];
#pragma unroll
    for (int i = 0; i < NQ; ++i) q[i] = hb4[(size_t)n * V + gl + 8 * i];
    __syncthreads();

    // --- scores: 8 lanes per neighbor, 32 neighbors in flight ---
    for (int j = grp; j < k; j += 32) {
        const float4* hm = hb4 + (size_t)s_nbr[j] * V;
        float4 m[NQ];
#pragma unroll
        for (int i = 0; i < NQ; ++i) m[i] = hm[gl + 8 * i];   // independent loads
        float p = 0.0f;
#pragma unroll
        for (int i = 0; i < NQ; ++i)
            p += q[i].x * m[i].x + q[i].y * m[i].y + q[i].z * m[i].z + q[i].w * m[i].w;
        p += __shfl_down(p, 4, 64);
        p += __shfl_down(p, 2, 64);
        p += __shfl_down(p, 1, 64);
        if (gl == 0) s_sc[j] = p;
    }
    __syncthreads();

    // --- masked max (dot==0 => masked_fill(NEG), torch semantics) ---
    float lm = -INFINITY;
    for (int j = t; j < k; j += 256) {
        float v = s_sc[j];
        if (v != 0.0f) lm = fmaxf(lm, v);
    }
    lm = wave_reduce_max(lm);
    if (lane == 0) s_red[wave] = lm;
    __syncthreads();
    const float mx = fmaxf(fmaxf(s_red[0], s_red[1]), fmaxf(s_red[2], s_red[3]));
    __syncthreads();

    // --- exp + sum ---
    float ls = 0.0f;
    for (int j = t; j < k; j += 256) {
        float v = s_sc[j];
        float w = (v != 0.0f) ? __expf(v - mx) : 0.0f;
        s_sc[j] = w;
        ls += w;
    }
    ls = wave_reduce_sum(ls);
    if (lane == 0) s_red[wave] = ls;
    __syncthreads();
    const float sum = s_red[0] + s_red[1] + s_red[2] + s_red[3];

    // --- aggregate: thread owns float4 slice v, 2-way unrolled gathers ---
    constexpr int G = 256 / V;         // 8 for D=128, 16 for D=64
    const int v = t % V;
    const int g = t / V;
    float4 acc0 = {0.0f, 0.0f, 0.0f, 0.0f};
    float4 acc1 = {0.0f, 0.0f, 0.0f, 0.0f};
    if (sum > 0.0f) {
        int j = g;
        for (; j + G < k; j += 2 * G) {
            float w0 = s_sc[j], w1 = s_sc[j + G];
            float4 m0 = hb4[(size_t)s_nbr[j] * V + v];       // independent
            float4 m1 = hb4[(size_t)s_nbr[j + G] * V + v];   // loads
            acc0.x += w0 * m0.x; acc0.y += w0 * m0.y;
            acc0.z += w0 * m0.z; acc0.w += w0 * m0.w;
            acc1.x += w1 * m1.x; acc1.y += w1 * m1.y;
            acc1.z += w1 * m1.z; acc1.w += w1 * m1.w;
        }
        if (j < k) {
            float w0 = s_sc[j];
            float4 m0 = hb4[(size_t)s_nbr[j] * V + v];
            acc0.x += w0 * m0.x; acc0.y += w0 * m0.y;
            acc0.z += w0 * m0.z; acc0.w += w0 * m0.w;
        }
        acc0.x += acc1.x; acc0.y += acc1.y; acc0.z += acc1.z; acc0.w += acc1.w;
    }
    s_acc[t] = acc0;
    __syncthreads();
    if (g == 0) {
#pragma unroll
        for (int gg = 1; gg < G; ++gg) {
            float4 o = s_acc[gg * V + v];
            acc0.x += o.x; acc0.y += o.y; acc0.z += o.z; acc0.w += o.w;
        }
        const float4 bi = ((const float4*)bias)[v];
        float4 o;
        if (sum > 0.0f) {
            const float inv = 1.0f / sum;
            o.x = acc0.x * inv + bi.x;
            o.y = acc0.y * inv + bi.y;
            o.z = acc0.z * inv + bi.z;
            o.w = acc0.w * inv + bi.w;
        } else {
            const float4 cs = ((const float4*)colsum)[b * V + v];
            constexpr float invN = 1.0f / (float)N_;
            o.x = cs.x * invN + bi.x;
            o.y = cs.y * invN + bi.y;
            o.z = cs.z * invN + bi.z;
            o.w = cs.w * invN + bi.w;
        }
        if (RELU) {
            o.x = fmaxf(o.x, 0.0f);
            o.y = fmaxf(o.y, 0.0f);
            o.z = fmaxf(o.z, 0.0f);
            o.w = fmaxf(o.w, 0.0f);
        }
        ((float4*)out)[((size_t)b * N_ + n) * V + v] = o;
    }
}

// ---------------------------------------------------------------------------
// Launch
// ---------------------------------------------------------------------------
extern "C" void kernel_launch(void* const* d_in, const int* in_sizes, int n_in,
                              void* d_out, int out_size, void* d_ws, size_t ws_size,
                              hipStream_t stream) {
    (void)in_sizes; (void)n_in; (void)out_size; (void)ws_size;

    const float* flow_x = (const float*)d_in[0];
    const float* graph  = (const float*)d_in[1];
    const float* W1     = (const float*)d_in[2];
    const float* b1     = (const float*)d_in[3];
    const float* W2     = (const float*)d_in[4];
    const float* b2     = (const float*)d_in[5];
    float* out = (float*)d_out;

    char* p = (char*)d_ws;
    auto carve = [&](size_t bytes) -> void* {
        void* r = (void*)p;
        p += (bytes + 255) & ~(size_t)255;
        return r;
    };
    int*   nbr_cnt = (int*)carve((size_t)N_ * sizeof(int));
    int*   nbr_idx = (int*)carve((size_t)N_ * MAXDEG * sizeof(int));
    float* h1      = (float*)carve((size_t)B_ * N_ * DHID * sizeof(float));
    float* x2      = (float*)carve((size_t)B_ * N_ * DHID * sizeof(float));
    float* h2      = (float*)carve((size_t)B_ * N_ * DOUT2 * sizeof(float));
    float* cm1     = (float*)carve((size_t)B_ * DHID * sizeof(float));
    float* cm2     = (float*)carve((size_t)B_ * DOUT2 * sizeof(float));

    // 1. adjacency -> neighbor lists (+ zero cm1/cm2)
    k_build_csr<<<N_, 256, 0, stream>>>(graph, nbr_cnt, nbr_idx, cm1, cm2);

    // 2. layer 1 linear (+ fused column sums)
    k_linear<DIN1, DHID><<<(B_ * N_) / 32, 256, 0, stream>>>(flow_x, W1, h1, cm1);

    // 3. layer 1 attention + bias + relu
    k_attn<DHID, true><<<N_ * B_, 256, 0, stream>>>(h1, nbr_cnt, nbr_idx, b1, cm1, x2);

    // 4. layer 2 linear (+ fused column sums)
    k_linear<DHID, DOUT2><<<(B_ * N_) / 32, 256, 0, stream>>>(x2, W2, h2, cm2);

    // 5. layer 2 attention + bias -> d_out  ([B,N,1,64] is flat-identical)
    k_attn<DOUT2, false><<<N_ * B_, 256, 0, stream>>>(h2, nbr_cnt, nbr_idx, b2, cm2, out);
}

// Round 4
// 313.867 us; speedup vs baseline: 2.6029x; 1.1543x over previous
//
#include <hip/hip_runtime.h>
#include <hip/hip_bf16.h>
#include <cmath>

// Problem constants
#define B_   8
#define N_   4096
#define DIN1 64
#define DHID 128
#define DOUT2 64
#define MAXDEG 256

// ---------------------------------------------------------------------------
// Kernel 1: adjacency -> fixed-stride neighbor lists (float4 scan).
// Blocks 0..7 also zero the column-sum fallback buffers.
// List order is irrelevant (softmax is order-independent).
// ---------------------------------------------------------------------------
__global__ __launch_bounds__(256) void k_build_csr(
    const float* __restrict__ graph, int* __restrict__ cnt, int* __restrict__ idx,
    float* __restrict__ cm1, float* __restrict__ cm2)
{
    const int n = blockIdx.x;
    if (n < B_) {
        for (int i = threadIdx.x; i < DHID; i += 256) cm1[n * DHID + i] = 0.0f;
        for (int i = threadIdx.x; i < DOUT2; i += 256) cm2[n * DOUT2 + i] = 0.0f;
    }
    __shared__ int lcnt;
    if (threadIdx.x == 0) lcnt = 0;
    __syncthreads();
    const float4* row4 = (const float4*)(graph + (size_t)n * N_);
    int* myidx = idx + (size_t)n * MAXDEG;
    for (int m4 = threadIdx.x; m4 < N_ / 4; m4 += 256) {
        float4 g = row4[m4];
        if (g.x != 0.0f) { int p = atomicAdd(&lcnt, 1); if (p < MAXDEG) myidx[p] = 4 * m4; }
        if (g.y != 0.0f) { int p = atomicAdd(&lcnt, 1); if (p < MAXDEG) myidx[p] = 4 * m4 + 1; }
        if (g.z != 0.0f) { int p = atomicAdd(&lcnt, 1); if (p < MAXDEG) myidx[p] = 4 * m4 + 2; }
        if (g.w != 0.0f) { int p = atomicAdd(&lcnt, 1); if (p < MAXDEG) myidx[p] = 4 * m4 + 3; }
    }
    __syncthreads();
    if (threadIdx.x == 0) cnt[n] = (lcnt < MAXDEG) ? lcnt : MAXDEG;
}

// ---------------------------------------------------------------------------
// Kernel 2: register-tiled linear. out[r,k] = sum_d x[r,d]*W[k,d].
// 32 rows/block. Thread tile = TR rows x 4 cols. W transposed in LDS
// (sWt[d][k], contiguous-k b128 reads = conflict-free BW floor); x fragments
// straight from global (L1 broadcast; block touches <=16KB of x).
// Barrier-free d-loop. Fused per-batch column sums for the softmax fallback.
// ---------------------------------------------------------------------------
template <int DIN, int DOUT>
__global__ __launch_bounds__(256) void k_linear(
    const float* __restrict__ x, const float* __restrict__ W,
    float* __restrict__ out, float* __restrict__ cm)
{
    constexpr int CG = DOUT / 4;     // col groups (32 or 16)
    constexpr int RG = 256 / CG;     // row groups (8 or 16)
    constexpr int TR = 32 / RG;      // rows per thread (4 or 2)

    __shared__ float sWt[DIN][DOUT + 4];
    __shared__ float scol[DOUT];

    const int t = threadIdx.x;
    // stage W transposed
    const float4* W4 = (const float4*)W;
    for (int i = t; i < DOUT * (DIN / 4); i += 256) {
        int kk = i / (DIN / 4);
        int d4 = i % (DIN / 4);
        float4 w = W4[i];
        sWt[4 * d4 + 0][kk] = w.x;
        sWt[4 * d4 + 1][kk] = w.y;
        sWt[4 * d4 + 2][kk] = w.z;
        sWt[4 * d4 + 3][kk] = w.w;
    }
    if (t < DOUT) scol[t] = 0.0f;
    __syncthreads();

    const int rg = t / CG;
    const int c  = t % CG;
    const int base = blockIdx.x * 32;
    const int b = base / N_;
    const float4* x4 = (const float4*)x;

    float acc[TR][4];
#pragma unroll
    for (int i = 0; i < TR; ++i)
#pragma unroll
        for (int j = 0; j < 4; ++j) acc[i][j] = 0.0f;

    for (int d4 = 0; d4 < DIN / 4; ++d4) {
        float4 xf[TR];
#pragma unroll
        for (int i = 0; i < TR; ++i)
            xf[i] = x4[(size_t)(base + rg * TR + i) * (DIN / 4) + d4];
        float4 wf[4];
#pragma unroll
        for (int dd = 0; dd < 4; ++dd)
            wf[dd] = *(const float4*)&sWt[4 * d4 + dd][4 * c];
#pragma unroll
        for (int i = 0; i < TR; ++i) {
            acc[i][0] += xf[i].x * wf[0].x + xf[i].y * wf[1].x + xf[i].z * wf[2].x + xf[i].w * wf[3].x;
            acc[i][1] += xf[i].x * wf[0].y + xf[i].y * wf[1].y + xf[i].z * wf[2].y + xf[i].w * wf[3].y;
            acc[i][2] += xf[i].x * wf[0].z + xf[i].y * wf[1].z + xf[i].z * wf[2].z + xf[i].w * wf[3].z;
            acc[i][3] += xf[i].x * wf[0].w + xf[i].y * wf[1].w + xf[i].z * wf[2].w + xf[i].w * wf[3].w;
        }
    }

    float colacc[4] = {0.0f, 0.0f, 0.0f, 0.0f};
#pragma unroll
    for (int i = 0; i < TR; ++i) {
        float4 o = {acc[i][0], acc[i][1], acc[i][2], acc[i][3]};
        ((float4*)out)[(size_t)(base + rg * TR + i) * CG + c] = o;
        colacc[0] += o.x; colacc[1] += o.y; colacc[2] += o.z; colacc[3] += o.w;
    }
#pragma unroll
    for (int j = 0; j < 4; ++j) atomicAdd(&scol[4 * c + j], colacc[j]);
    __syncthreads();
    if (t < DOUT) atomicAdd(&cm[b * DOUT + t], scol[t]);
}

// ---------------------------------------------------------------------------
// Kernel 3: query-tiled sparse masked attention. One block = 8 queries x 1
// batch; grid 4096, b = bid&7 pins batches to XCDs. Wave w owns queries
// 2w,2w+1 end-to-end through scores+softmax (wave-internal, barrier-free);
// single __syncthreads before the aggregate phase. Exact torch
// masked_fill(s==0) semantics + uniform-softmax fallback via colsum.
// ---------------------------------------------------------------------------
template <int D, bool RELU>
__global__ __launch_bounds__(256) void k_attn(
    const float* __restrict__ h, const int* __restrict__ cnt,
    const int* __restrict__ idx, const float* __restrict__ bias,
    const float* __restrict__ colsum, float* __restrict__ out)
{
    constexpr int V    = D / 4;                  // float4s per row (32 or 16)
    constexpr int GRPL = (D == 128) ? 8 : 4;     // lanes per neighbor dot
    constexpr int NQ   = V / GRPL;               // float4s per lane (4)
    constexpr int GPW  = 64 / GRPL;              // neighbor groups per wave

    const int bid = blockIdx.x;
    const int b  = bid & 7;
    const int n0 = (bid >> 3) * 8;
    const int t = threadIdx.x;
    const int lane = t & 63;
    const int wave = t >> 6;

    __shared__ int   s_cnt[8];
    __shared__ int   s_nbr[8][MAXDEG];
    __shared__ float s_sc[8][MAXDEG];
    __shared__ float s_sum[8];
    __shared__ float4 s_acc[(D == 64) ? 256 : 1];

    if (t < 8) s_cnt[t] = cnt[n0 + t];
    __syncthreads();

    const float4* __restrict__ hb4 = (const float4*)(h + (size_t)b * N_ * D);
    const int grp = lane / GRPL;
    const int gl  = lane % GRPL;

    // --- scores + softmax: wave w handles queries 2w, 2w+1 (no barriers) ---
#pragma unroll
    for (int qq = 0; qq < 2; ++qq) {
        const int q  = 2 * wave + qq;
        const int kq = s_cnt[q];
        for (int j = lane; j < kq; j += 64)
            s_nbr[q][j] = idx[(size_t)(n0 + q) * MAXDEG + j];
        float4 qf[NQ];
#pragma unroll
        for (int i = 0; i < NQ; ++i) qf[i] = hb4[(size_t)(n0 + q) * V + gl + GRPL * i];
        for (int j = grp; j < kq; j += GPW) {
            const float4* hm = hb4 + (size_t)s_nbr[q][j] * V;
            float4 m[NQ];
#pragma unroll
            for (int i = 0; i < NQ; ++i) m[i] = hm[gl + GRPL * i];
            float p = 0.0f;
#pragma unroll
            for (int i = 0; i < NQ; ++i)
                p += qf[i].x * m[i].x + qf[i].y * m[i].y + qf[i].z * m[i].z + qf[i].w * m[i].w;
            if constexpr (GRPL == 8) p += __shfl_down(p, 4, 64);
            p += __shfl_down(p, 2, 64);
            p += __shfl_down(p, 1, 64);
            if (gl == 0) s_sc[q][j] = p;
        }
    }

    // softmax: 32-lane group per query (same wave that wrote s_sc -> no barrier)
    {
        const int qi = t >> 5;
        const int sj = t & 31;
        const int kq = s_cnt[qi];
        float lm = -INFINITY;
        for (int j = sj; j < kq; j += 32) {
            float v = s_sc[qi][j];
            if (v != 0.0f) lm = fmaxf(lm, v);   // dot==0 => masked_fill(NEG)
        }
#pragma unroll
        for (int off = 16; off > 0; off >>= 1) lm = fmaxf(lm, __shfl_down(lm, off, 64));
        const float mx = __shfl(lm, lane & 32, 64);
        float ls = 0.0f;
        for (int j = sj; j < kq; j += 32) {
            float v = s_sc[qi][j];
            float w = (v != 0.0f) ? __expf(v - mx) : 0.0f;
            s_sc[qi][j] = w;
            ls += w;
        }
#pragma unroll
        for (int off = 16; off > 0; off >>= 1) ls += __shfl_down(ls, off, 64);
        if (sj == 0) s_sum[qi] = ls;
    }
    __syncthreads();   // the one barrier: aggregate reads cross-wave LDS

    // --- aggregate ---
    if constexpr (D == 128) {
        const int qi = t >> 5;          // 8 queries x 32 f4-slices = 256
        const int v  = t & 31;
        const float sum = s_sum[qi];
        const int  kq  = s_cnt[qi];
        float4 a0 = {0, 0, 0, 0}, a1 = {0, 0, 0, 0};
        float4 o;
        const float4 bi = ((const float4*)bias)[v];
        if (sum > 0.0f) {
            int j = 0;
            for (; j + 1 < kq; j += 2) {
                float w0 = s_sc[qi][j], w1 = s_sc[qi][j + 1];
                float4 m0 = hb4[(size_t)s_nbr[qi][j] * V + v];
                float4 m1 = hb4[(size_t)s_nbr[qi][j + 1] * V + v];
                a0.x += w0 * m0.x; a0.y += w0 * m0.y; a0.z += w0 * m0.z; a0.w += w0 * m0.w;
                a1.x += w1 * m1.x; a1.y += w1 * m1.y; a1.z += w1 * m1.z; a1.w += w1 * m1.w;
            }
            if (j < kq) {
                float w0 = s_sc[qi][j];
                float4 m0 = hb4[(size_t)s_nbr[qi][j] * V + v];
                a0.x += w0 * m0.x; a0.y += w0 * m0.y; a0.z += w0 * m0.z; a0.w += w0 * m0.w;
            }
            const float inv = 1.0f / sum;
            o.x = (a0.x + a1.x) * inv + bi.x;
            o.y = (a0.y + a1.y) * inv + bi.y;
            o.z = (a0.z + a1.z) * inv + bi.z;
            o.w = (a0.w + a1.w) * inv + bi.w;
        } else {
            const float4 cs = ((const float4*)colsum)[b * V + v];
            constexpr float invN = 1.0f / (float)N_;
            o.x = cs.x * invN + bi.x; o.y = cs.y * invN + bi.y;
            o.z = cs.z * invN + bi.z; o.w = cs.w * invN + bi.w;
        }
        if (RELU) {
            o.x = fmaxf(o.x, 0.0f); o.y = fmaxf(o.y, 0.0f);
            o.z = fmaxf(o.z, 0.0f); o.w = fmaxf(o.w, 0.0f);
        }
        ((float4*)out)[((size_t)b * N_ + n0 + qi) * V + v] = o;
    } else {
        const int qi = t >> 5;          // 8 queries x (2 j-groups x 16 f4-slices)
        const int jg = (t >> 4) & 1;
        const int v  = t & 15;
        const float sum = s_sum[qi];
        const int  kq  = s_cnt[qi];
        float4 a0 = {0, 0, 0, 0}, a1 = {0, 0, 0, 0};
        if (sum > 0.0f) {
            int j = jg;
            for (; j + 2 < kq; j += 4) {
                float w0 = s_sc[qi][j], w1 = s_sc[qi][j + 2];
                float4 m0 = hb4[(size_t)s_nbr[qi][j] * V + v];
                float4 m1 = hb4[(size_t)s_nbr[qi][j + 2] * V + v];
                a0.x += w0 * m0.x; a0.y += w0 * m0.y; a0.z += w0 * m0.z; a0.w += w0 * m0.w;
                a1.x += w1 * m1.x; a1.y += w1 * m1.y; a1.z += w1 * m1.z; a1.w += w1 * m1.w;
            }
            if (j < kq) {
                float w0 = s_sc[qi][j];
                float4 m0 = hb4[(size_t)s_nbr[qi][j] * V + v];
                a0.x += w0 * m0.x; a0.y += w0 * m0.y; a0.z += w0 * m0.z; a0.w += w0 * m0.w;
            }
            a0.x += a1.x; a0.y += a1.y; a0.z += a1.z; a0.w += a1.w;
        }
        s_acc[t] = a0;                  // pair-reduce within the same wave
        if (jg == 0) {
            float4 p2 = s_acc[t + 16];
            float4 o;
            const float4 bi = ((const float4*)bias)[v];
            if (sum > 0.0f) {
                const float inv = 1.0f / sum;
                o.x = (a0.x + p2.x) * inv + bi.x;
                o.y = (a0.y + p2.y) * inv + bi.y;
                o.z = (a0.z + p2.z) * inv + bi.z;
                o.w = (a0.w + p2.w) * inv + bi.w;
            } else {
                const float4 cs = ((const float4*)colsum)[b * V + v];
                constexpr float invN = 1.0f / (float)N_;
                o.x = cs.x * invN + bi.x; o.y = cs.y * invN + bi.y;
                o.z = cs.z * invN + bi.z; o.w = cs.w * invN + bi.w;
            }
            if (RELU) {
                o.x = fmaxf(o.x, 0.0f); o.y = fmaxf(o.y, 0.0f);
                o.z = fmaxf(o.z, 0.0f); o.w = fmaxf(o.w, 0.0f);
            }
            ((float4*)out)[((size_t)b * N_ + n0 + qi) * V + v] = o;
        }
    }
}

// ---------------------------------------------------------------------------
// Launch
// ---------------------------------------------------------------------------
extern "C" void kernel_launch(void* const* d_in, const int* in_sizes, int n_in,
                              void* d_out, int out_size, void* d_ws, size_t ws_size,
                              hipStream_t stream) {
    (void)in_sizes; (void)n_in; (void)out_size; (void)ws_size;

    const float* flow_x = (const float*)d_in[0];
    const float* graph  = (const float*)d_in[1];
    const float* W1     = (const float*)d_in[2];
    const float* b1     = (const float*)d_in[3];
    const float* W2     = (const float*)d_in[4];
    const float* b2     = (const float*)d_in[5];
    float* out = (float*)d_out;

    char* p = (char*)d_ws;
    auto carve = [&](size_t bytes) -> void* {
        void* r = (void*)p;
        p += (bytes + 255) & ~(size_t)255;
        return r;
    };
    int*   nbr_cnt = (int*)carve((size_t)N_ * sizeof(int));
    int*   nbr_idx = (int*)carve((size_t)N_ * MAXDEG * sizeof(int));
    float* h1      = (float*)carve((size_t)B_ * N_ * DHID * sizeof(float));
    float* x2      = (float*)carve((size_t)B_ * N_ * DHID * sizeof(float));
    float* h2      = (float*)carve((size_t)B_ * N_ * DOUT2 * sizeof(float));
    float* cm1     = (float*)carve((size_t)B_ * DHID * sizeof(float));
    float* cm2     = (float*)carve((size_t)B_ * DOUT2 * sizeof(float));

    // 1. adjacency -> neighbor lists (+ zero cm1/cm2)
    k_build_csr<<<N_, 256, 0, stream>>>(graph, nbr_cnt, nbr_idx, cm1, cm2);

    // 2. layer 1 linear (+ fused column sums)
    k_linear<DIN1, DHID><<<(B_ * N_) / 32, 256, 0, stream>>>(flow_x, W1, h1, cm1);

    // 3. layer 1 attention + bias + relu
    k_attn<DHID, true><<<N_ * B_ / 8, 256, 0, stream>>>(h1, nbr_cnt, nbr_idx, b1, cm1, x2);

    // 4. layer 2 linear (+ fused column sums)
    k_linear<DHID, DOUT2><<<(B_ * N_) / 32, 256, 0, stream>>>(x2, W2, h2, cm2);

    // 5. layer 2 attention + bias -> d_out  ([B,N,1,64] is flat-identical)
    k_attn<DOUT2, false><<<N_ * B_ / 8, 256, 0, stream>>>(h2, nbr_cnt, nbr_idx, b2, cm2, out);
}

// Round 5
// 282.308 us; speedup vs baseline: 2.8939x; 1.1118x over previous
//
#include <hip/hip_runtime.h>
#include <hip/hip_bf16.h>
#include <cmath>

// Problem constants
#define B_   8
#define N_   4096
#define DIN1 64
#define DHID 128
#define DOUT2 64
#define MAXDEG 256

// ---------------------------------------------------------------------------
// Kernel 1: adjacency -> fixed-stride neighbor lists (float4 scan).
// Blocks 0..7 also zero the column-sum fallback buffers.
// ---------------------------------------------------------------------------
__global__ __launch_bounds__(256) void k_build_csr(
    const float* __restrict__ graph, int* __restrict__ cnt, int* __restrict__ idx,
    float* __restrict__ cm1, float* __restrict__ cm2)
{
    const int n = blockIdx.x;
    if (n < B_) {
        for (int i = threadIdx.x; i < DHID; i += 256) cm1[n * DHID + i] = 0.0f;
        for (int i = threadIdx.x; i < DOUT2; i += 256) cm2[n * DOUT2 + i] = 0.0f;
    }
    __shared__ int lcnt;
    if (threadIdx.x == 0) lcnt = 0;
    __syncthreads();
    const float4* row4 = (const float4*)(graph + (size_t)n * N_);
    int* myidx = idx + (size_t)n * MAXDEG;
    for (int m4 = threadIdx.x; m4 < N_ / 4; m4 += 256) {
        float4 g = row4[m4];
        if (g.x != 0.0f) { int p = atomicAdd(&lcnt, 1); if (p < MAXDEG) myidx[p] = 4 * m4; }
        if (g.y != 0.0f) { int p = atomicAdd(&lcnt, 1); if (p < MAXDEG) myidx[p] = 4 * m4 + 1; }
        if (g.z != 0.0f) { int p = atomicAdd(&lcnt, 1); if (p < MAXDEG) myidx[p] = 4 * m4 + 2; }
        if (g.w != 0.0f) { int p = atomicAdd(&lcnt, 1); if (p < MAXDEG) myidx[p] = 4 * m4 + 3; }
    }
    __syncthreads();
    if (threadIdx.x == 0) cnt[n] = (lcnt < MAXDEG) ? lcnt : MAXDEG;
}

// ---------------------------------------------------------------------------
// Kernel 2: register-tiled linear with fused per-batch column sums.
// ---------------------------------------------------------------------------
template <int DIN, int DOUT>
__global__ __launch_bounds__(256) void k_linear(
    const float* __restrict__ x, const float* __restrict__ W,
    float* __restrict__ out, float* __restrict__ cm)
{
    constexpr int CG = DOUT / 4;
    constexpr int RG = 256 / CG;
    constexpr int TR = 32 / RG;

    __shared__ float sWt[DIN][DOUT + 4];
    __shared__ float scol[DOUT];

    const int t = threadIdx.x;
    const float4* W4 = (const float4*)W;
    for (int i = t; i < DOUT * (DIN / 4); i += 256) {
        int kk = i / (DIN / 4);
        int d4 = i % (DIN / 4);
        float4 w = W4[i];
        sWt[4 * d4 + 0][kk] = w.x;
        sWt[4 * d4 + 1][kk] = w.y;
        sWt[4 * d4 + 2][kk] = w.z;
        sWt[4 * d4 + 3][kk] = w.w;
    }
    if (t < DOUT) scol[t] = 0.0f;
    __syncthreads();

    const int rg = t / CG;
    const int c  = t % CG;
    const int base = blockIdx.x * 32;
    const int b = base / N_;
    const float4* x4 = (const float4*)x;

    float acc[TR][4];
#pragma unroll
    for (int i = 0; i < TR; ++i)
#pragma unroll
        for (int j = 0; j < 4; ++j) acc[i][j] = 0.0f;

    for (int d4 = 0; d4 < DIN / 4; ++d4) {
        float4 xf[TR];
#pragma unroll
        for (int i = 0; i < TR; ++i)
            xf[i] = x4[(size_t)(base + rg * TR + i) * (DIN / 4) + d4];
        float4 wf[4];
#pragma unroll
        for (int dd = 0; dd < 4; ++dd)
            wf[dd] = *(const float4*)&sWt[4 * d4 + dd][4 * c];
#pragma unroll
        for (int i = 0; i < TR; ++i) {
            acc[i][0] += xf[i].x * wf[0].x + xf[i].y * wf[1].x + xf[i].z * wf[2].x + xf[i].w * wf[3].x;
            acc[i][1] += xf[i].x * wf[0].y + xf[i].y * wf[1].y + xf[i].z * wf[2].y + xf[i].w * wf[3].y;
            acc[i][2] += xf[i].x * wf[0].z + xf[i].y * wf[1].z + xf[i].z * wf[2].z + xf[i].w * wf[3].z;
            acc[i][3] += xf[i].x * wf[0].w + xf[i].y * wf[1].w + xf[i].z * wf[2].w + xf[i].w * wf[3].w;
        }
    }

    float colacc[4] = {0.0f, 0.0f, 0.0f, 0.0f};
#pragma unroll
    for (int i = 0; i < TR; ++i) {
        float4 o = {acc[i][0], acc[i][1], acc[i][2], acc[i][3]};
        ((float4*)out)[(size_t)(base + rg * TR + i) * CG + c] = o;
        colacc[0] += o.x; colacc[1] += o.y; colacc[2] += o.z; colacc[3] += o.w;
    }
#pragma unroll
    for (int j = 0; j < 4; ++j) atomicAdd(&scol[4 * c + j], colacc[j]);
    __syncthreads();
    if (t < DOUT) atomicAdd(&cm[b * DOUT + t], scol[t]);
}

// ---------------------------------------------------------------------------
// Kernel 3: ONLINE-SOFTMAX sparse masked attention. One query per wave;
// 4 groups of 16 lanes stream disjoint neighbor subsets. Each neighbor row
// is loaded from L2 exactly ONCE (registers serve both the dot and the
// accumulate) -> halves L2 traffic vs the two-phase scheme. Dot via 4-deep
// shfl_xor (all 16 lanes converge); flash-style (m,s,acc) running state;
// group states merged with 2 xor-shuffle stages. Zero __syncthreads.
// Exact torch masked_fill(s==0) semantics + uniform-softmax fallback.
// ---------------------------------------------------------------------------
template <int D, bool RELU>
__global__ __launch_bounds__(256) void k_attn(
    const float* __restrict__ h, const int* __restrict__ cnt,
    const int* __restrict__ idx, const float* __restrict__ bias,
    const float* __restrict__ colsum, float* __restrict__ out)
{
    constexpr int V  = D / 4;    // float4s per row (32 or 16)
    constexpr int NF = V / 16;   // float4s per lane (2 or 1)

    const int bid  = blockIdx.x;
    const int b    = bid & 7;                    // batch -> XCD pinning
    const int wave = threadIdx.x >> 6;
    const int lane = threadIdx.x & 63;
    const int n    = (bid >> 3) * 4 + wave;      // one query per wave
    const int grp  = lane >> 4;                  // 4 neighbor streams
    const int gl   = lane & 15;

    __shared__ int s_nbr[4][MAXDEG];             // wave-private -> no barrier

    const int k = cnt[n];
    for (int j = lane; j < k; j += 64)
        s_nbr[wave][j] = idx[(size_t)n * MAXDEG + j];

    const float4* __restrict__ hb4 = (const float4*)(h + (size_t)b * N_ * D);
    float4 qf[NF];
#pragma unroll
    for (int i = 0; i < NF; ++i) qf[i] = hb4[(size_t)n * V + gl + 16 * i];

    float m = -INFINITY, s = 0.0f;
    float4 acc[NF];
#pragma unroll
    for (int i = 0; i < NF; ++i) acc[i] = {0.0f, 0.0f, 0.0f, 0.0f};

    // one-ahead pipelined neighbor loop
    float4 r[NF];
    int j = grp;
    if (j < k) {
        const float4* hm = hb4 + (size_t)s_nbr[wave][j] * V;
#pragma unroll
        for (int i = 0; i < NF; ++i) r[i] = hm[gl + 16 * i];
    }
    while (j < k) {
        float4 cur[NF];
#pragma unroll
        for (int i = 0; i < NF; ++i) cur[i] = r[i];
        const int jn = j + 4;
        if (jn < k) {
            const float4* hm = hb4 + (size_t)s_nbr[wave][jn] * V;
#pragma unroll
            for (int i = 0; i < NF; ++i) r[i] = hm[gl + 16 * i];
        }
        float p = 0.0f;
#pragma unroll
        for (int i = 0; i < NF; ++i)
            p += qf[i].x * cur[i].x + qf[i].y * cur[i].y
               + qf[i].z * cur[i].z + qf[i].w * cur[i].w;
        p += __shfl_xor(p, 8, 64);
        p += __shfl_xor(p, 4, 64);
        p += __shfl_xor(p, 2, 64);
        p += __shfl_xor(p, 1, 64);
        if (p != 0.0f) {                          // dot==0 => masked (torch)
            if (p > m) {
                const float f = __expf(m - p);    // m=-inf first time -> f=0
                s = s * f + 1.0f;
#pragma unroll
                for (int i = 0; i < NF; ++i) {
                    acc[i].x = acc[i].x * f + cur[i].x;
                    acc[i].y = acc[i].y * f + cur[i].y;
                    acc[i].z = acc[i].z * f + cur[i].z;
                    acc[i].w = acc[i].w * f + cur[i].w;
                }
                m = p;
            } else {
                const float e = __expf(p - m);
                s += e;
#pragma unroll
                for (int i = 0; i < NF; ++i) {
                    acc[i].x += e * cur[i].x;
                    acc[i].y += e * cur[i].y;
                    acc[i].z += e * cur[i].z;
                    acc[i].w += e * cur[i].w;
                }
            }
        }
        j = jn;
    }

    // merge the 4 group states (xor 16, then 32); all 64 lanes converge
#pragma unroll
    for (int mask = 16; mask <= 32; mask <<= 1) {
        const float m2 = __shfl_xor(m, mask, 64);
        const float s2 = __shfl_xor(s, mask, 64);
        float4 a2[NF];
#pragma unroll
        for (int i = 0; i < NF; ++i) {
            a2[i].x = __shfl_xor(acc[i].x, mask, 64);
            a2[i].y = __shfl_xor(acc[i].y, mask, 64);
            a2[i].z = __shfl_xor(acc[i].z, mask, 64);
            a2[i].w = __shfl_xor(acc[i].w, mask, 64);
        }
        const float mm = fmaxf(m, m2);
        const float f1 = (m  == mm) ? 1.0f : __expf(m  - mm);  // -inf guard
        const float f2 = (m2 == mm) ? 1.0f : __expf(m2 - mm);
        s = s * f1 + s2 * f2;
#pragma unroll
        for (int i = 0; i < NF; ++i) {
            acc[i].x = acc[i].x * f1 + a2[i].x * f2;
            acc[i].y = acc[i].y * f1 + a2[i].y * f2;
            acc[i].z = acc[i].z * f1 + a2[i].z * f2;
            acc[i].w = acc[i].w * f1 + a2[i].w * f2;
        }
        m = mm;
    }

    // epilogue: group 0 writes the row
    if (lane < 16) {
        const float4* bias4 = (const float4*)bias;
        float4 o[NF];
        if (s > 0.0f) {
            const float inv = 1.0f / s;
#pragma unroll
            for (int i = 0; i < NF; ++i) {
                const float4 bi = bias4[gl + 16 * i];
                o[i].x = acc[i].x * inv + bi.x;
                o[i].y = acc[i].y * inv + bi.y;
                o[i].z = acc[i].z * inv + bi.z;
                o[i].w = acc[i].w * inv + bi.w;
            }
        } else {                                  // all-masked: uniform softmax
            constexpr float invN = 1.0f / (float)N_;
#pragma unroll
            for (int i = 0; i < NF; ++i) {
                const float4 cs = ((const float4*)colsum)[b * V + gl + 16 * i];
                const float4 bi = bias4[gl + 16 * i];
                o[i].x = cs.x * invN + bi.x;
                o[i].y = cs.y * invN + bi.y;
                o[i].z = cs.z * invN + bi.z;
                o[i].w = cs.w * invN + bi.w;
            }
        }
#pragma unroll
        for (int i = 0; i < NF; ++i) {
            if (RELU) {
                o[i].x = fmaxf(o[i].x, 0.0f); o[i].y = fmaxf(o[i].y, 0.0f);
                o[i].z = fmaxf(o[i].z, 0.0f); o[i].w = fmaxf(o[i].w, 0.0f);
            }
            ((float4*)out)[((size_t)b * N_ + n) * V + gl + 16 * i] = o[i];
        }
    }
}

// ---------------------------------------------------------------------------
// Launch
// ---------------------------------------------------------------------------
extern "C" void kernel_launch(void* const* d_in, const int* in_sizes, int n_in,
                              void* d_out, int out_size, void* d_ws, size_t ws_size,
                              hipStream_t stream) {
    (void)in_sizes; (void)n_in; (void)out_size; (void)ws_size;

    const float* flow_x = (const float*)d_in[0];
    const float* graph  = (const float*)d_in[1];
    const float* W1     = (const float*)d_in[2];
    const float* b1     = (const float*)d_in[3];
    const float* W2     = (const float*)d_in[4];
    const float* b2     = (const float*)d_in[5];
    float* out = (float*)d_out;

    char* p = (char*)d_ws;
    auto carve = [&](size_t bytes) -> void* {
        void* r = (void*)p;
        p += (bytes + 255) & ~(size_t)255;
        return r;
    };
    int*   nbr_cnt = (int*)carve((size_t)N_ * sizeof(int));
    int*   nbr_idx = (int*)carve((size_t)N_ * MAXDEG * sizeof(int));
    float* h1      = (float*)carve((size_t)B_ * N_ * DHID * sizeof(float));
    float* x2      = (float*)carve((size_t)B_ * N_ * DHID * sizeof(float));
    float* h2      = (float*)carve((size_t)B_ * N_ * DOUT2 * sizeof(float));
    float* cm1     = (float*)carve((size_t)B_ * DHID * sizeof(float));
    float* cm2     = (float*)carve((size_t)B_ * DOUT2 * sizeof(float));

    // 1. adjacency -> neighbor lists (+ zero cm1/cm2)
    k_build_csr<<<N_, 256, 0, stream>>>(graph, nbr_cnt, nbr_idx, cm1, cm2);

    // 2. layer 1 linear (+ fused column sums)
    k_linear<DIN1, DHID><<<(B_ * N_) / 32, 256, 0, stream>>>(flow_x, W1, h1, cm1);

    // 3. layer 1 attention + bias + relu (one query per wave)
    k_attn<DHID, true><<<N_ * B_ / 4, 256, 0, stream>>>(h1, nbr_cnt, nbr_idx, b1, cm1, x2);

    // 4. layer 2 linear (+ fused column sums)
    k_linear<DHID, DOUT2><<<(B_ * N_) / 32, 256, 0, stream>>>(x2, W2, h2, cm2);

    // 5. layer 2 attention + bias -> d_out  ([B,N,1,64] is flat-identical)
    k_attn<DOUT2, false><<<N_ * B_ / 4, 256, 0, stream>>>(h2, nbr_cnt, nbr_idx, b2, cm2, out);
}

// Round 6
// 270.410 us; speedup vs baseline: 3.0212x; 1.0440x over previous
//
#include <hip/hip_runtime.h>
#include <hip/hip_bf16.h>
#include <cmath>

// Problem constants
#define B_   8
#define N_   4096
#define DIN1 64
#define DHID 128
#define DOUT2 64
#define MAXDEG 256

// ---------------------------------------------------------------------------
// Kernel 1: adjacency -> fixed-stride neighbor lists (float4 scan).
// ---------------------------------------------------------------------------
__global__ __launch_bounds__(256) void k_build_csr(
    const float* __restrict__ graph, int* __restrict__ cnt, int* __restrict__ idx)
{
    const int n = blockIdx.x;
    __shared__ int lcnt;
    if (threadIdx.x == 0) lcnt = 0;
    __syncthreads();
    const float4* row4 = (const float4*)(graph + (size_t)n * N_);
    int* myidx = idx + (size_t)n * MAXDEG;
    for (int m4 = threadIdx.x; m4 < N_ / 4; m4 += 256) {
        float4 g = row4[m4];
        if (g.x != 0.0f) { int p = atomicAdd(&lcnt, 1); if (p < MAXDEG) myidx[p] = 4 * m4; }
        if (g.y != 0.0f) { int p = atomicAdd(&lcnt, 1); if (p < MAXDEG) myidx[p] = 4 * m4 + 1; }
        if (g.z != 0.0f) { int p = atomicAdd(&lcnt, 1); if (p < MAXDEG) myidx[p] = 4 * m4 + 2; }
        if (g.w != 0.0f) { int p = atomicAdd(&lcnt, 1); if (p < MAXDEG) myidx[p] = 4 * m4 + 3; }
    }
    __syncthreads();
    if (threadIdx.x == 0) cnt[n] = (lcnt < MAXDEG) ? lcnt : MAXDEG;
}

// ---------------------------------------------------------------------------
// Kernel 2: register-tiled linear (no atomic colsum tail anymore).
// out[r,k] = sum_d x[r,d]*W[k,d]. 32 rows/block, thread tile TR rows x 4 cols.
// ---------------------------------------------------------------------------
template <int DIN, int DOUT>
__global__ __launch_bounds__(256) void k_linear(
    const float* __restrict__ x, const float* __restrict__ W,
    float* __restrict__ out)
{
    constexpr int CG = DOUT / 4;
    constexpr int RG = 256 / CG;
    constexpr int TR = 32 / RG;

    __shared__ float sWt[DIN][DOUT + 4];

    const int t = threadIdx.x;
    const float4* W4 = (const float4*)W;
    for (int i = t; i < DOUT * (DIN / 4); i += 256) {
        int kk = i / (DIN / 4);
        int d4 = i % (DIN / 4);
        float4 w = W4[i];
        sWt[4 * d4 + 0][kk] = w.x;
        sWt[4 * d4 + 1][kk] = w.y;
        sWt[4 * d4 + 2][kk] = w.z;
        sWt[4 * d4 + 3][kk] = w.w;
    }
    __syncthreads();

    const int rg = t / CG;
    const int c  = t % CG;
    const int base = blockIdx.x * 32;
    const float4* x4 = (const float4*)x;

    float acc[TR][4];
#pragma unroll
    for (int i = 0; i < TR; ++i)
#pragma unroll
        for (int j = 0; j < 4; ++j) acc[i][j] = 0.0f;

    for (int d4 = 0; d4 < DIN / 4; ++d4) {
        float4 xf[TR];
#pragma unroll
        for (int i = 0; i < TR; ++i)
            xf[i] = x4[(size_t)(base + rg * TR + i) * (DIN / 4) + d4];
        float4 wf[4];
#pragma unroll
        for (int dd = 0; dd < 4; ++dd)
            wf[dd] = *(const float4*)&sWt[4 * d4 + dd][4 * c];
#pragma unroll
        for (int i = 0; i < TR; ++i) {
            acc[i][0] += xf[i].x * wf[0].x + xf[i].y * wf[1].x + xf[i].z * wf[2].x + xf[i].w * wf[3].x;
            acc[i][1] += xf[i].x * wf[0].y + xf[i].y * wf[1].y + xf[i].z * wf[2].y + xf[i].w * wf[3].y;
            acc[i][2] += xf[i].x * wf[0].z + xf[i].y * wf[1].z + xf[i].z * wf[2].z + xf[i].w * wf[3].z;
            acc[i][3] += xf[i].x * wf[0].w + xf[i].y * wf[1].w + xf[i].z * wf[2].w + xf[i].w * wf[3].w;
        }
    }

#pragma unroll
    for (int i = 0; i < TR; ++i) {
        float4 o = {acc[i][0], acc[i][1], acc[i][2], acc[i][3]};
        ((float4*)out)[(size_t)(base + rg * TR + i) * CG + c] = o;
    }
}

// ---------------------------------------------------------------------------
// Kernel 3: online-softmax sparse masked attention. One query per wave;
// 8 groups of 8 lanes stream disjoint neighbor subsets (each neighbor row
// read from L2 exactly once). Lazy rescale: the (m,s,acc) state only rescales
// when p > m+60 (overflow-safe: e^60*256 << fp32 max; final acc/s is
// offset-invariant). 3-stage xor-shuffle group merge; zero __syncthreads.
// Exact torch masked_fill(s==0) semantics; the all-masked uniform-softmax
// fallback is an in-kernel rare path (recompute column mean of h[b]) --
// self-loop makes it dead code unless a whole h row is exactly zero.
// ---------------------------------------------------------------------------
template <int D, bool RELU>
__global__ __launch_bounds__(256) void k_attn(
    const float* __restrict__ h, const int* __restrict__ cnt,
    const int* __restrict__ idx, const float* __restrict__ bias,
    float* __restrict__ out)
{
    constexpr int V  = D / 4;   // float4s per row (32 or 16)
    constexpr int NF = V / 8;   // float4s per lane (4 or 2)

    const int bid  = blockIdx.x;
    const int b    = bid & 7;                    // batch -> XCD pinning
    const int wave = threadIdx.x >> 6;
    const int lane = threadIdx.x & 63;
    const int n    = (bid >> 3) * 4 + wave;      // one query per wave
    const int grp  = lane >> 3;                  // 8 neighbor streams
    const int gl   = lane & 7;

    __shared__ int s_nbr[4][MAXDEG];             // wave-private -> no barrier

    const int k = cnt[n];
    for (int j = lane; j < k; j += 64)
        s_nbr[wave][j] = idx[(size_t)n * MAXDEG + j];

    const float4* __restrict__ hb4 = (const float4*)(h + (size_t)b * N_ * D);
    float4 qf[NF];
#pragma unroll
    for (int i = 0; i < NF; ++i) qf[i] = hb4[(size_t)n * V + gl + 8 * i];

    float m = -INFINITY, s = 0.0f;
    float4 acc[NF];
#pragma unroll
    for (int i = 0; i < NF; ++i) acc[i] = {0.0f, 0.0f, 0.0f, 0.0f};

    // one-ahead pipelined neighbor loop
    float4 r[NF];
    int j = grp;
    if (j < k) {
        const float4* hm = hb4 + (size_t)s_nbr[wave][j] * V;
#pragma unroll
        for (int i = 0; i < NF; ++i) r[i] = hm[gl + 8 * i];
    }
    while (j < k) {
        float4 cur[NF];
#pragma unroll
        for (int i = 0; i < NF; ++i) cur[i] = r[i];
        const int jn = j + 8;
        if (jn < k) {
            const float4* hm = hb4 + (size_t)s_nbr[wave][jn] * V;
#pragma unroll
            for (int i = 0; i < NF; ++i) r[i] = hm[gl + 8 * i];
        }
        float p = 0.0f;
#pragma unroll
        for (int i = 0; i < NF; ++i)
            p += qf[i].x * cur[i].x + qf[i].y * cur[i].y
               + qf[i].z * cur[i].z + qf[i].w * cur[i].w;
        p += __shfl_xor(p, 4, 64);
        p += __shfl_xor(p, 2, 64);
        p += __shfl_xor(p, 1, 64);
        if (p != 0.0f) {                          // dot==0 => masked (torch)
            if (p > m + 60.0f) {                  // lazy rescale (rare)
                const float f = __expf(m - p);    // m=-inf first time -> 0
                s = s * f + 1.0f;
#pragma unroll
                for (int i = 0; i < NF; ++i) {
                    acc[i].x = acc[i].x * f + cur[i].x;
                    acc[i].y = acc[i].y * f + cur[i].y;
                    acc[i].z = acc[i].z * f + cur[i].z;
                    acc[i].w = acc[i].w * f + cur[i].w;
                }
                m = p;
            } else {                              // common path: no rescale
                const float e = __expf(p - m);    // arg <= 60 -> <= 1.1e26
                s += e;
#pragma unroll
                for (int i = 0; i < NF; ++i) {
                    acc[i].x += e * cur[i].x;
                    acc[i].y += e * cur[i].y;
                    acc[i].z += e * cur[i].z;
                    acc[i].w += e * cur[i].w;
                }
            }
        }
        j = jn;
    }

    // merge the 8 group states (xor 8, 16, 32); all 64 lanes converge
#pragma unroll
    for (int mask = 8; mask <= 32; mask <<= 1) {
        const float m2 = __shfl_xor(m, mask, 64);
        const float s2 = __shfl_xor(s, mask, 64);
        float4 a2[NF];
#pragma unroll
        for (int i = 0; i < NF; ++i) {
            a2[i].x = __shfl_xor(acc[i].x, mask, 64);
            a2[i].y = __shfl_xor(acc[i].y, mask, 64);
            a2[i].z = __shfl_xor(acc[i].z, mask, 64);
            a2[i].w = __shfl_xor(acc[i].w, mask, 64);
        }
        const float mm = fmaxf(m, m2);
        const float f1 = (m  == mm) ? 1.0f : __expf(m  - mm);  // -inf guard
        const float f2 = (m2 == mm) ? 1.0f : __expf(m2 - mm);
        s = s * f1 + s2 * f2;
#pragma unroll
        for (int i = 0; i < NF; ++i) {
            acc[i].x = acc[i].x * f1 + a2[i].x * f2;
            acc[i].y = acc[i].y * f1 + a2[i].y * f2;
            acc[i].z = acc[i].z * f1 + a2[i].z * f2;
            acc[i].w = acc[i].w * f1 + a2[i].w * f2;
        }
        m = mm;
    }

    if (s > 0.0f) {
        // normal epilogue: group 0 (lanes 0..7) writes the row
        if (grp == 0) {
            const float4* bias4 = (const float4*)bias;
            const float inv = 1.0f / s;
#pragma unroll
            for (int i = 0; i < NF; ++i) {
                const float4 bi = bias4[gl + 8 * i];
                float4 o;
                o.x = acc[i].x * inv + bi.x;
                o.y = acc[i].y * inv + bi.y;
                o.z = acc[i].z * inv + bi.z;
                o.w = acc[i].w * inv + bi.w;
                if (RELU) {
                    o.x = fmaxf(o.x, 0.0f); o.y = fmaxf(o.y, 0.0f);
                    o.z = fmaxf(o.z, 0.0f); o.w = fmaxf(o.w, 0.0f);
                }
                ((float4*)out)[((size_t)b * N_ + n) * V + gl + 8 * i] = o;
            }
        }
    } else {
        // RARE path (all scores masked): uniform softmax over all N rows ->
        // column mean of h[b]. Wave-uniform branch; ~2MB read, never taken
        // in practice (self-score = ||h||^2 > 0 unless the h row is all-zero).
        constexpr int RS = 64 / V;               // row streams (2 or 4)
        const int sl = lane % V;                 // slice index
        const int rs = lane / V;
        float4 a = {0.0f, 0.0f, 0.0f, 0.0f};
        for (int row = rs; row < N_; row += RS) {
            float4 v = hb4[(size_t)row * V + sl];
            a.x += v.x; a.y += v.y; a.z += v.z; a.w += v.w;
        }
#pragma unroll
        for (int mask = V; mask < 64; mask <<= 1) {
            a.x += __shfl_xor(a.x, mask, 64);
            a.y += __shfl_xor(a.y, mask, 64);
            a.z += __shfl_xor(a.z, mask, 64);
            a.w += __shfl_xor(a.w, mask, 64);
        }
        if (lane < V) {
            constexpr float invN = 1.0f / (float)N_;
            const float4 bi = ((const float4*)bias)[sl];
            float4 o;
            o.x = a.x * invN + bi.x;
            o.y = a.y * invN + bi.y;
            o.z = a.z * invN + bi.z;
            o.w = a.w * invN + bi.w;
            if (RELU) {
                o.x = fmaxf(o.x, 0.0f); o.y = fmaxf(o.y, 0.0f);
                o.z = fmaxf(o.z, 0.0f); o.w = fmaxf(o.w, 0.0f);
            }
            ((float4*)out)[((size_t)b * N_ + n) * V + sl] = o;
        }
    }
}

// ---------------------------------------------------------------------------
// Launch
// ---------------------------------------------------------------------------
extern "C" void kernel_launch(void* const* d_in, const int* in_sizes, int n_in,
                              void* d_out, int out_size, void* d_ws, size_t ws_size,
                              hipStream_t stream) {
    (void)in_sizes; (void)n_in; (void)out_size; (void)ws_size;

    const float* flow_x = (const float*)d_in[0];
    const float* graph  = (const float*)d_in[1];
    const float* W1     = (const float*)d_in[2];
    const float* b1     = (const float*)d_in[3];
    const float* W2     = (const float*)d_in[4];
    const float* b2     = (const float*)d_in[5];
    float* out = (float*)d_out;

    char* p = (char*)d_ws;
    auto carve = [&](size_t bytes) -> void* {
        void* r = (void*)p;
        p += (bytes + 255) & ~(size_t)255;
        return r;
    };
    int*   nbr_cnt = (int*)carve((size_t)N_ * sizeof(int));
    int*   nbr_idx = (int*)carve((size_t)N_ * MAXDEG * sizeof(int));
    float* h1      = (float*)carve((size_t)B_ * N_ * DHID * sizeof(float));
    float* x2      = (float*)carve((size_t)B_ * N_ * DHID * sizeof(float));
    float* h2      = (float*)carve((size_t)B_ * N_ * DOUT2 * sizeof(float));

    // 1. adjacency -> neighbor lists
    k_build_csr<<<N_, 256, 0, stream>>>(graph, nbr_cnt, nbr_idx);

    // 2. layer 1 linear
    k_linear<DIN1, DHID><<<(B_ * N_) / 32, 256, 0, stream>>>(flow_x, W1, h1);

    // 3. layer 1 attention + bias + relu (one query per wave)
    k_attn<DHID, true><<<N_ * B_ / 4, 256, 0, stream>>>(h1, nbr_cnt, nbr_idx, b1, x2);

    // 4. layer 2 linear
    k_linear<DHID, DOUT2><<<(B_ * N_) / 32, 256, 0, stream>>>(x2, W2, h2);

    // 5. layer 2 attention + bias -> d_out  ([B,N,1,64] is flat-identical)
    k_attn<DOUT2, false><<<N_ * B_ / 4, 256, 0, stream>>>(h2, nbr_cnt, nbr_idx, b2, out);
}